// Round 4
// baseline (321.135 us; speedup 1.0000x reference)
//
#include <hip/hip_runtime.h>
#include <cstdint>
#include <cstddef>

#define NN 32
#define NODE_ELEMS 1605632  // 8*56*56*64 elements per slot (NHWC); bf16 storage

typedef unsigned __int128 u128;
typedef __attribute__((ext_vector_type(8))) short bf16x8;
typedef __attribute__((ext_vector_type(4))) float f32x4;

// ---------------- host: replicate np.random.default_rng(0).random((32,32)) < 0.25 ----
static void compute_adj(bool adj[NN][NN]) {
  uint32_t pool[4];
  uint32_t hc = 0x43b0d7e5u;
  auto hashmix = [&hc](uint32_t v) -> uint32_t {
    v ^= hc; hc *= 0x931e8875u; v *= hc; v ^= v >> 16; return v;
  };
  auto mix = [](uint32_t x, uint32_t y) -> uint32_t {
    uint32_t r = x * 0xca01f9ddu - y * 0x4973f715u; r ^= r >> 16; return r;
  };
  for (int i = 0; i < 4; i++) pool[i] = hashmix(0u);
  for (int s = 0; s < 4; s++)
    for (int d = 0; d < 4; d++)
      if (s != d) pool[d] = mix(pool[d], hashmix(pool[s]));
  uint32_t hb = 0x8b51f9ddu;
  uint32_t w[8];
  for (int k = 0; k < 8; k++) {
    uint32_t v = pool[k & 3];
    v ^= hb; hb *= 0x58f38dedu; v *= hb; v ^= v >> 16;
    w[k] = v;
  }
  uint64_t s64[4];
  for (int j = 0; j < 4; j++) s64[j] = (uint64_t)w[2 * j] | ((uint64_t)w[2 * j + 1] << 32);
  u128 initstate = ((u128)s64[0] << 64) | s64[1];
  u128 initseq   = ((u128)s64[2] << 64) | s64[3];
  const u128 MULT = ((u128)0x2360ED051FC65DA4ULL << 64) | 0x4385DF649FCCF645ULL;
  u128 state = 0;
  u128 inc = (initseq << 1) | 1;
  state = state * MULT + inc;
  state += initstate;
  state = state * MULT + inc;
  for (int i = 0; i < NN; i++)
    for (int j = 0; j < NN; j++) {
      state = state * MULT + inc;
      uint64_t hi = (uint64_t)(state >> 64), lo = (uint64_t)state;
      unsigned rot = (unsigned)(hi >> 58);
      uint64_t xr = hi ^ lo;
      uint64_t out = (xr >> rot) | (xr << ((64u - rot) & 63u));
      double dv = (double)(out >> 11) * (1.0 / 9007199254740992.0);
      adj[i][j] = (dv < 0.25);
    }
}

// ---------------- device ----------------
struct NodeDesc {
  uint8_t node, npred, slot, flags;
  uint8_t pred_slot[31];
  uint8_t pad;
};
struct GroupArg { int n; NodeDesc d[32]; };   // one launch per LEVEL
struct FinalArg { int nf; uint8_t slot[32]; };

__device__ __forceinline__ float bf2f_lo(unsigned int w) {
  union { unsigned int u; float f; } c; c.u = w << 16; return c.f;
}
__device__ __forceinline__ float bf2f_hi(unsigned int w) {
  union { unsigned int u; float f; } c; c.u = w & 0xFFFF0000u; return c.f;
}
__device__ __forceinline__ float bf2f(unsigned short h) {
  union { unsigned int u; float f; } c; c.u = ((unsigned int)h) << 16; return c.f;
}
__device__ __forceinline__ unsigned short f2bf(float f) {
  union { float f; unsigned int u; } c; c.f = f;
  unsigned int u = c.u + 0x7FFFu + ((c.u >> 16) & 1u);  // RNE
  return (unsigned short)(u >> 16);
}

// R28:
// (1) input_kernel: x staging via 5 aligned float4 loads/row instead of 17
//     scalar loads (ix0 = 16*(m%7)-1 === 3 mod 4, so the window phase is
//     constant). R27 counters: input_kernel 46us, VALUBusy 16%, scattered
//     scalar loads = 64 cache lines per instr.
// (2) level_kernel: B1 barrier removed (all threads compute the uniform
//     sigmoid weights in-register per 4-pred batch; bit-identical), so
//     aggregation loads issue from instruction 1.
// (3) level_kernel: 16-position tiles (2x8 output) -> halo 4x10x64 (10KB),
//     LDS ~20.5KB (was 28.2), grid 1568*n (1568%8==0 keeps image<->XCD),
//     per-block critical path halves, blocks/CU 5 -> 6-7.
__global__ __launch_bounds__(256) void input_kernel(
    GroupArg g,
    const float* __restrict__ x,
    const float* __restrict__ dwall,
    const float* __restrict__ pwall,
    const float* __restrict__ gmall,
    const float* __restrict__ btall,
    const float* __restrict__ mnall,
    const float* __restrict__ vrall,
    unsigned short* __restrict__ wsb)
{
  __shared__ float xtile[9 * 17 * 64];                  // [9r][17c][64ch] relu(x) fp32
  __shared__ __align__(16) unsigned short pwb[4096];    // pw weights (bf16, swz)
  __shared__ __align__(16) unsigned short tbuf[2048];   // t[32 pos][64 c] (bf16, swz)

  const int b = blockIdx.x & 7;       // image == XCD
  const int m = blockIdx.x >> 3;      // tile [0,98)
  const int t = threadIdx.x;
  const int ty = (m / 7) * 4;         // 14 y-tiles of 4 rows (output 56x56)
  const int tx = (m % 7) * 8;         // 7 x-tiles of 8 cols

  const int dwc = t & 63;
  const int pbase = (t >> 6) * 8;

  // ---- stage relu(x) tile once: input rows 2ty-1..2ty+7, cols 2tx-1..2tx+15
  // ix0 = 2tx-1 === 3 (mod 4) -> aligned window base xbase = ix0-3.
  // rel col r in [0,16]: r=0 -> v0.w ; r=1..4 -> v1 ; 5..8 -> v2 ; 9..12 -> v3 ;
  // 13..16 -> v4. Left edge (xbase<0): v0 zeroed (rel0 is gx=-1 -> 0 anyway).
  {
    const int r0 = t >> 6;
    const float* xb = x + (size_t)(b * 64 + dwc) * 12544;
    const int iy0 = ty * 2 - 1;
    const int xbase = tx * 2 - 4;     // aligned to 16B
    for (int iyL = r0; iyL < 9; iyL += 4) {
      int gy = iy0 + iyL;
      bool rowok = ((unsigned)gy < 112u);
      const float* row = xb + gy * 112 + xbase;
      float4 z = make_float4(0.f, 0.f, 0.f, 0.f);
      float4 v0 = z, v1 = z, v2 = z, v3 = z, v4 = z;
      if (rowok) {
        if (xbase >= 0) v0 = *(const float4*)(row);
        v1 = *(const float4*)(row + 4);
        v2 = *(const float4*)(row + 8);
        v3 = *(const float4*)(row + 12);
        v4 = *(const float4*)(row + 16);
      }
      float* dst = xtile + (iyL * 17) * 64 + dwc;
      dst[0 * 64]  = fmaxf(v0.w, 0.f);
      dst[1 * 64]  = fmaxf(v1.x, 0.f);
      dst[2 * 64]  = fmaxf(v1.y, 0.f);
      dst[3 * 64]  = fmaxf(v1.z, 0.f);
      dst[4 * 64]  = fmaxf(v1.w, 0.f);
      dst[5 * 64]  = fmaxf(v2.x, 0.f);
      dst[6 * 64]  = fmaxf(v2.y, 0.f);
      dst[7 * 64]  = fmaxf(v2.z, 0.f);
      dst[8 * 64]  = fmaxf(v2.w, 0.f);
      dst[9 * 64]  = fmaxf(v3.x, 0.f);
      dst[10 * 64] = fmaxf(v3.y, 0.f);
      dst[11 * 64] = fmaxf(v3.z, 0.f);
      dst[12 * 64] = fmaxf(v3.w, 0.f);
      dst[13 * 64] = fmaxf(v4.x, 0.f);
      dst[14 * 64] = fmaxf(v4.y, 0.f);
      dst[15 * 64] = fmaxf(v4.z, 0.f);
      dst[16 * 64] = fmaxf(v4.w, 0.f);
    }
  }

  for (int kk = 0; kk < g.n; kk++) {
    const NodeDesc nd = g.d[kk];
    const int node = nd.node;

    __syncthreads();  // B_a: xtile ready (kk=0); prev MFMA done with pwb/tbuf

    // stage pw (issue global loads early; latency hides under depthwise VALU)
    {
      const float* pwn = pwall + node * 4096;
      #pragma unroll
      for (int i = 0; i < 16; i++) {
        int gidx = t + 256 * i;
        int o = gidx >> 6, cc = gidx & 63;
        pwb[o * 64 + ((((cc >> 3) ^ (o & 7)) << 3) | (cc & 7))] = f2bf(pwn[gidx]);
      }
    }

    const float* k9 = dwall + (node * 64 + dwc) * 9;
    float kk9[9];
    #pragma unroll
    for (int q = 0; q < 9; q++) kk9[q] = k9[q];

    // depthwise stride-2 from LDS xtile
    float tv[8];
    #pragma unroll
    for (int jj = 0; jj < 8; jj++) {
      int p = pbase + jj;
      int py = p >> 3, px = p & 7;
      const float* r0 = xtile + ((py * 2) * 17 + px * 2) * 64 + dwc;
      tv[jj] = r0[0]    * kk9[0] + r0[64]   * kk9[1] + r0[128]  * kk9[2]
             + r0[1088] * kk9[3] + r0[1152] * kk9[4] + r0[1216] * kk9[5]
             + r0[2176] * kk9[6] + r0[2240] * kk9[7] + r0[2304] * kk9[8];
    }

    // t matrix bf16, granule-swizzled
    #pragma unroll
    for (int jj = 0; jj < 8; jj++) {
      int p = pbase + jj;
      tbuf[p * 64 + ((((dwc >> 3) ^ (p & 7)) << 3) | (dwc & 7))] = f2bf(tv[jj]);
    }
    __syncthreads();  // B_b: tbuf + pwb ready

    // MFMA pointwise: D[32 pos][64 oc] = t x pw^T
    const int lane = t & 63;
    const int wave = t >> 6;
    const int mtile = wave & 1;
    const int npair = wave >> 1;
    const int lm = lane & 15;
    const int quad = lane >> 4;

    bf16x8 afrag[2];
    #pragma unroll
    for (int ks = 0; ks < 2; ks++) {
      int pos = mtile * 16 + lm;
      int gg = ks * 4 + quad;
      afrag[ks] = *(const bf16x8*)&tbuf[pos * 64 + ((gg ^ (pos & 7)) << 3)];
    }
    f32x4 acc[2];
    #pragma unroll
    for (int nt = 0; nt < 2; nt++) {
      acc[nt] = (f32x4){0.f, 0.f, 0.f, 0.f};
      int oc = (npair * 2 + nt) * 16 + lm;
      #pragma unroll
      for (int ks = 0; ks < 2; ks++) {
        int gg = ks * 4 + quad;
        bf16x8 bfrag = *(const bf16x8*)&pwb[oc * 64 + ((gg ^ (oc & 7)) << 3)];
        acc[nt] = __builtin_amdgcn_mfma_f32_16x16x32_bf16(afrag[ks], bfrag, acc[nt], 0, 0, 0);
      }
    }

    // BN + bf16 slot store
    unsigned short* slotp = wsb + (size_t)nd.slot * NODE_ELEMS;
    #pragma unroll
    for (int nt = 0; nt < 2; nt++) {
      int oc = (npair * 2 + nt) * 16 + lm;
      int gi = node * 64 + oc;
      float inv = gmall[gi] / sqrtf(vrall[gi] + 1e-5f);
      float mn = mnall[gi], btv = btall[gi];
      #pragma unroll
      for (int rr = 0; rr < 4; rr++) {
        int pos = mtile * 16 + quad * 4 + rr;
        int gy = ty + (pos >> 3), gx = tx + (pos & 7);
        size_t base = (((size_t)(b * 56 + gy)) * 56 + gx) * 64 + oc;
        slotp[base] = f2bf((acc[nt][rr] - mn) * inv + btv);
      }
    }
  }
}

// Levels >= 1: node-parallel, one (node, 16-pos tile) per block.
// 16 positions = 2 out rows x 8 out cols; halo 4x10x64 fp32 (10KB).
// Grid 1568*n (1568 = 196 tiles * 8 images, %8==0 -> image<->XCD kept).
__global__ __launch_bounds__(256) void level_kernel(
    GroupArg g,
    const float* __restrict__ dwall,
    const float* __restrict__ pwall,
    const float* __restrict__ gmall,
    const float* __restrict__ btall,
    const float* __restrict__ mnall,
    const float* __restrict__ vrall,
    const float* __restrict__ aggw,
    unsigned short* __restrict__ wsb)   // bf16 slots
{
  __shared__ float smem[2560];                          // halo [4r][10c][64ch] fp32
  __shared__ __align__(16) unsigned short pwb[4096];    // pw weights (bf16, swz)
  __shared__ __align__(16) unsigned short tbuf[1024];   // t[16 pos][64 c] (bf16, swz)

  const int bid = blockIdx.x;
  const int nid = bid / 1568;         // node index within this level
  const int r   = bid - nid * 1568;
  const int b = r & 7;                // image == XCD
  const int m = r >> 3;               // tile [0,196)
  const int t = threadIdx.x;
  const int ty = (m / 7) * 2;         // 28 y-tiles of 2 rows
  const int tx = (m % 7) * 8;         // 7 x-tiles of 8 cols

  const NodeDesc nd = g.d[nid];
  const int node = nd.node;

  const int dwc = t & 63;
  const int pbase = (t >> 6) * 4;     // 4 positions per thread

  const float* k9 = dwall + (node * 64 + dwc) * 9;
  float kk9[9];
  #pragma unroll
  for (int q = 0; q < 9; q++) kk9[q] = k9[q];

  // aggregate + relu into fp32 NHWC halo (320 units of 8 ch = 16 B)
  const int np = nd.npred;
  float sa[2][8];
  int off[2];
  bool inb[2];
  #pragma unroll
  for (int u = 0; u < 2; u++) {
    int idx = t + u * 256;
    bool valid = (u == 0) || (t < 64);
    int pos = idx >> 3, q8 = idx & 7;
    int hy = pos / 10, hx = pos - hy * 10;
    int gy = ty + hy - 1, gx = tx + hx - 1;
    inb[u] = valid && ((unsigned)gy < 56u) && ((unsigned)gx < 56u);
    off[u] = ((b * 56 + gy) * 56 + gx) * 64 + q8 * 8;
    #pragma unroll
    for (int q = 0; q < 8; q++) sa[u][q] = 0.f;
  }
  // no barrier: weights are computed per-thread (uniform), loads issue now
  for (int p0 = 0; p0 < np; p0 += 4) {
    uint4 v[4][2];
    #pragma unroll
    for (int pp = 0; pp < 4; pp++) {
      if (p0 + pp < np) {
        const unsigned short* pb = wsb + (size_t)nd.pred_slot[p0 + pp] * NODE_ELEMS;
        #pragma unroll
        for (int u = 0; u < 2; u++)
          if (inb[u]) v[pp][u] = *(const uint4*)(pb + off[u]);
      }
    }
    float wv4[4];
    #pragma unroll
    for (int pp = 0; pp < 4; pp++)
      if (p0 + pp < np)
        wv4[pp] = (np == 1) ? 1.0f
                            : 1.f / (1.f + expf(-aggw[node * 32 + p0 + pp]));
    #pragma unroll
    for (int pp = 0; pp < 4; pp++) {
      if (p0 + pp < np) {
        float wv = wv4[pp];
        #pragma unroll
        for (int u = 0; u < 2; u++) {
          if (inb[u]) {
            sa[u][0] = fmaf(wv, bf2f_lo(v[pp][u].x), sa[u][0]);
            sa[u][1] = fmaf(wv, bf2f_hi(v[pp][u].x), sa[u][1]);
            sa[u][2] = fmaf(wv, bf2f_lo(v[pp][u].y), sa[u][2]);
            sa[u][3] = fmaf(wv, bf2f_hi(v[pp][u].y), sa[u][3]);
            sa[u][4] = fmaf(wv, bf2f_lo(v[pp][u].z), sa[u][4]);
            sa[u][5] = fmaf(wv, bf2f_hi(v[pp][u].z), sa[u][5]);
            sa[u][6] = fmaf(wv, bf2f_lo(v[pp][u].w), sa[u][6]);
            sa[u][7] = fmaf(wv, bf2f_hi(v[pp][u].w), sa[u][7]);
          }
        }
      }
    }
  }
  #pragma unroll
  for (int u = 0; u < 2; u++) {
    int idx = t + u * 256;
    if ((u == 0) || (t < 64)) {
      float4 s0 = make_float4(fmaxf(sa[u][0], 0.f), fmaxf(sa[u][1], 0.f),
                              fmaxf(sa[u][2], 0.f), fmaxf(sa[u][3], 0.f));
      float4 s1 = make_float4(fmaxf(sa[u][4], 0.f), fmaxf(sa[u][5], 0.f),
                              fmaxf(sa[u][6], 0.f), fmaxf(sa[u][7], 0.f));
      *(float4*)&smem[idx * 8] = s0;
      *(float4*)&smem[idx * 8 + 4] = s1;
    }
  }
  // stage pw (overlaps the B2 wait; consumed after B3)
  {
    const float* pwn = pwall + node * 4096;
    #pragma unroll
    for (int i = 0; i < 16; i++) {
      int gidx = t + 256 * i;
      int o = gidx >> 6, cc = gidx & 63;
      pwb[o * 64 + ((((cc >> 3) ^ (o & 7)) << 3) | (cc & 7))] = f2bf(pwn[gidx]);
    }
  }
  __syncthreads();   // B2: halo ready
  float tv[4];
  #pragma unroll
  for (int jj = 0; jj < 4; jj++) {
    int p = pbase + jj;
    int py = p >> 3, px = p & 7;
    const float* r0 = smem + (py * 10 + px) * 64 + dwc;
    tv[jj] = r0[0]    * kk9[0] + r0[64]   * kk9[1] + r0[128]  * kk9[2]
           + r0[640]  * kk9[3] + r0[704]  * kk9[4] + r0[768]  * kk9[5]
           + r0[1280] * kk9[6] + r0[1344] * kk9[7] + r0[1408] * kk9[8];
  }

  // t matrix bf16, granule-swizzled: (p,c) -> p*64 + (((c>>3)^(p&7))<<3)|(c&7)
  #pragma unroll
  for (int jj = 0; jj < 4; jj++) {
    int p = pbase + jj;
    tbuf[p * 64 + ((((dwc >> 3) ^ (p & 7)) << 3) | (dwc & 7))] = f2bf(tv[jj]);
  }
  __syncthreads();   // B3: tbuf + pwb ready

  // MFMA pointwise: D[16 pos][64 oc] = t x pw^T; wave w owns oc block w*16
  const int lane = t & 63;
  const int wave = t >> 6;
  const int lm = lane & 15;
  const int quad = lane >> 4;

  bf16x8 afrag[2];
  #pragma unroll
  for (int ks = 0; ks < 2; ks++) {
    int pos = lm;
    int gg = ks * 4 + quad;
    afrag[ks] = *(const bf16x8*)&tbuf[pos * 64 + ((gg ^ (pos & 7)) << 3)];
  }
  const int oc = wave * 16 + lm;
  f32x4 acc = (f32x4){0.f, 0.f, 0.f, 0.f};
  #pragma unroll
  for (int ks = 0; ks < 2; ks++) {
    int gg = ks * 4 + quad;
    bf16x8 bfrag = *(const bf16x8*)&pwb[oc * 64 + ((gg ^ (oc & 7)) << 3)];
    acc = __builtin_amdgcn_mfma_f32_16x16x32_bf16(afrag[ks], bfrag, acc, 0, 0, 0);
  }

  // BN + bf16 slot store. D: col=lane&15 (oc), row=quad*4+reg (pos in tile)
  unsigned short* slotp = wsb + (size_t)nd.slot * NODE_ELEMS;
  {
    int gi = node * 64 + oc;
    float inv = gmall[gi] / sqrtf(vrall[gi] + 1e-5f);
    float mn = mnall[gi], btv = btall[gi];
    #pragma unroll
    for (int rr = 0; rr < 4; rr++) {
      int pos = quad * 4 + rr;
      int gy = ty + (pos >> 3), gx = tx + (pos & 7);
      size_t base = (((size_t)(b * 56 + gy)) * 56 + gx) * 64 + oc;
      slotp[base] = f2bf((acc[rr] - mn) * inv + btv);
    }
  }
}

// Mean of FINAL bf16 slots (fp32 accumulate) -> NCHW d_out.
// Block per (b, y, half-x): 8*56*2 = 896 blocks. uint4 loads (8 bf16),
// slot loop batched 4-wide into named regs -> 4 loads in flight.
__global__ __launch_bounds__(256) void finalize_kernel(
    FinalArg fa, const unsigned short* __restrict__ wsb,
    float* __restrict__ out, float inv_nf)
{
  __shared__ float lds[64 * 29];      // [c][x-half] transpose buffer, pad 29
  const int bid = blockIdx.x;
  const int half = bid & 1;
  const int by = bid >> 1;
  const int b = by / 56, y = by - b * 56;
  const int x0 = half * 28;
  const size_t rbase = ((((size_t)b * 56 + y) * 56) + x0) * 64;  // [x][c] bf16
  const int t = threadIdx.x;
  const int nf = fa.nf;

  if (t < 224) {                      // 28 x * 8 channel-groups of 8
    const int xx = t >> 3, q8 = t & 7;
    const unsigned short* p0 = wsb + rbase + xx * 64 + q8 * 8;
    float s0 = 0.f, s1 = 0.f, s2 = 0.f, s3 = 0.f,
          s4 = 0.f, s5 = 0.f, s6 = 0.f, s7 = 0.f;
    for (int f0 = 0; f0 < nf; f0 += 4) {
      uint4 va, vb, vc, vd;
      if (f0 + 0 < nf) va = *(const uint4*)(p0 + (size_t)fa.slot[f0 + 0] * NODE_ELEMS);
      if (f0 + 1 < nf) vb = *(const uint4*)(p0 + (size_t)fa.slot[f0 + 1] * NODE_ELEMS);
      if (f0 + 2 < nf) vc = *(const uint4*)(p0 + (size_t)fa.slot[f0 + 2] * NODE_ELEMS);
      if (f0 + 3 < nf) vd = *(const uint4*)(p0 + (size_t)fa.slot[f0 + 3] * NODE_ELEMS);
      if (f0 + 0 < nf) {
        s0 += bf2f_lo(va.x); s1 += bf2f_hi(va.x); s2 += bf2f_lo(va.y); s3 += bf2f_hi(va.y);
        s4 += bf2f_lo(va.z); s5 += bf2f_hi(va.z); s6 += bf2f_lo(va.w); s7 += bf2f_hi(va.w);
      }
      if (f0 + 1 < nf) {
        s0 += bf2f_lo(vb.x); s1 += bf2f_hi(vb.x); s2 += bf2f_lo(vb.y); s3 += bf2f_hi(vb.y);
        s4 += bf2f_lo(vb.z); s5 += bf2f_hi(vb.z); s6 += bf2f_lo(vb.w); s7 += bf2f_hi(vb.w);
      }
      if (f0 + 2 < nf) {
        s0 += bf2f_lo(vc.x); s1 += bf2f_hi(vc.x); s2 += bf2f_lo(vc.y); s3 += bf2f_hi(vc.y);
        s4 += bf2f_lo(vc.z); s5 += bf2f_hi(vc.z); s6 += bf2f_lo(vc.w); s7 += bf2f_hi(vc.w);
      }
      if (f0 + 3 < nf) {
        s0 += bf2f_lo(vd.x); s1 += bf2f_hi(vd.x); s2 += bf2f_lo(vd.y); s3 += bf2f_hi(vd.y);
        s4 += bf2f_lo(vd.z); s5 += bf2f_hi(vd.z); s6 += bf2f_lo(vd.w); s7 += bf2f_hi(vd.w);
      }
    }
    float* dl = lds + (q8 * 8) * 29 + xx;
    dl[0 * 29] = s0 * inv_nf; dl[1 * 29] = s1 * inv_nf;
    dl[2 * 29] = s2 * inv_nf; dl[3 * 29] = s3 * inv_nf;
    dl[4 * 29] = s4 * inv_nf; dl[5 * 29] = s5 * inv_nf;
    dl[6 * 29] = s6 * inv_nf; dl[7 * 29] = s7 * inv_nf;
  }
  __syncthreads();
  float* dst = out + (size_t)b * 64 * 3136 + (size_t)y * 56 + x0;
  for (int j = t; j < 1792; j += 256) {     // 64 c * 28 x
    int c = j / 28, xx = j - c * 28;
    dst[(size_t)c * 3136 + xx] = lds[c * 29 + xx];
  }
}

// ---------------- launcher ----------------
extern "C" void kernel_launch(void* const* d_in, const int* in_sizes, int n_in,
                              void* d_out, int out_size, void* d_ws, size_t ws_size,
                              hipStream_t stream) {
  (void)in_sizes; (void)n_in; (void)ws_size; (void)out_size;
  const float* x     = (const float*)d_in[0];
  const float* dw    = (const float*)d_in[1];
  const float* pw    = (const float*)d_in[2];
  const float* gamma = (const float*)d_in[3];
  const float* beta  = (const float*)d_in[4];
  const float* mean  = (const float*)d_in[5];
  const float* var   = (const float*)d_in[6];
  const float* aggw  = (const float*)d_in[7];
  unsigned short* wsb = (unsigned short*)d_ws;
  float* out = (float*)d_out;

  bool adj[NN][NN];
  compute_adj(adj);

  int npred[NN], preds[NN][NN], nsucc[NN], ispan[NN], level[NN];
  for (int j = 0; j < NN; j++) {
    npred[j] = 0;
    for (int i = 0; i < j; i++) if (adj[i][j]) preds[j][npred[j]++] = i;
  }
  for (int i = 0; i < NN; i++) {
    nsucc[i] = 0; ispan[i] = NN;
    int mx = -1;
    for (int j = i + 1; j < NN; j++) if (adj[i][j]) { nsucc[i]++; mx = j; }
    if (nsucc[i] > 0) ispan[i] = mx;
  }
  int maxlev = 0;
  for (int j = 0; j < NN; j++) {
    int lv = 0;
    for (int p = 0; p < npred[j]; p++) {
      int cand = level[preds[j][p]] + 1;
      if (cand > lv) lv = cand;
    }
    level[j] = lv;
    if (lv > maxlev) maxlev = lv;
  }
  bool isfinal[NN]; int nf = 0;
  for (int i = 0; i < NN; i++) { isfinal[i] = (ispan[i] >= NN - 1); if (isfinal[i]) nf++; }
  int lastlvl[NN];
  for (int i = 0; i < NN; i++) {
    lastlvl[i] = -1;
    for (int j = i + 1; j < NN; j++) if (adj[i][j] && level[j] > lastlvl[i]) lastlvl[i] = level[j];
  }
  // slot allocation: every node gets a slot; FINAL slots never freed.
  int slot[NN]; bool used[NN];
  for (int s = 0; s < NN; s++) used[s] = false;
  for (int L = 0; L <= maxlev; L++) {
    for (int i = 0; i < NN; i++) {
      if (level[i] != L) continue;
      int s = 0; while (used[s]) s++;
      used[s] = true; slot[i] = s;
    }
    for (int i = 0; i < NN; i++)
      if (level[i] <= L && !isfinal[i] && lastlvl[i] == L)
        used[slot[i]] = false;
  }

  float inv_nf = 1.0f / (float)nf;

  for (int L = 0; L <= maxlev; L++) {
    GroupArg g; g.n = 0;
    for (int i = 0; i < NN; i++) {
      if (level[i] != L) continue;
      NodeDesc& nd = g.d[g.n++];
      nd.node = (uint8_t)i;
      nd.npred = (uint8_t)npred[i];
      nd.slot = (uint8_t)slot[i];
      nd.flags = 0;
      for (int p = 0; p < npred[i]; p++) nd.pred_slot[p] = (uint8_t)slot[preds[i][p]];
    }
    if (g.n > 0) {
      if (L == 0) {
        input_kernel<<<784, 256, 0, stream>>>(g, x, dw, pw, gamma, beta,
                                              mean, var, wsb);
      } else {
        level_kernel<<<1568 * g.n, 256, 0, stream>>>(g, dw, pw, gamma, beta,
                                                     mean, var, aggw, wsb);
      }
    }
  }

  FinalArg fa; fa.nf = 0;
  for (int i = 0; i < NN; i++) if (isfinal[i]) fa.slot[fa.nf++] = (uint8_t)slot[i];
  finalize_kernel<<<896, 256, 0, stream>>>(fa, wsb, out, inv_nf);
}

// Round 5
// 221.377 us; speedup vs baseline: 1.4506x; 1.4506x over previous
//
#include <hip/hip_runtime.h>
#include <cstdint>
#include <cstddef>

#define NN 32
#define NODE_ELEMS 1605632  // 8*56*56*64 elements per slot (NHWC); bf16 storage

typedef unsigned __int128 u128;
typedef __attribute__((ext_vector_type(8))) short bf16x8;
typedef __attribute__((ext_vector_type(4))) float f32x4;

// ---------------- host: replicate np.random.default_rng(0).random((32,32)) < 0.25 ----
static void compute_adj(bool adj[NN][NN]) {
  uint32_t pool[4];
  uint32_t hc = 0x43b0d7e5u;
  auto hashmix = [&hc](uint32_t v) -> uint32_t {
    v ^= hc; hc *= 0x931e8875u; v *= hc; v ^= v >> 16; return v;
  };
  auto mix = [](uint32_t x, uint32_t y) -> uint32_t {
    uint32_t r = x * 0xca01f9ddu - y * 0x4973f715u; r ^= r >> 16; return r;
  };
  for (int i = 0; i < 4; i++) pool[i] = hashmix(0u);
  for (int s = 0; s < 4; s++)
    for (int d = 0; d < 4; d++)
      if (s != d) pool[d] = mix(pool[d], hashmix(pool[s]));
  uint32_t hb = 0x8b51f9ddu;
  uint32_t w[8];
  for (int k = 0; k < 8; k++) {
    uint32_t v = pool[k & 3];
    v ^= hb; hb *= 0x58f38dedu; v *= hb; v ^= v >> 16;
    w[k] = v;
  }
  uint64_t s64[4];
  for (int j = 0; j < 4; j++) s64[j] = (uint64_t)w[2 * j] | ((uint64_t)w[2 * j + 1] << 32);
  u128 initstate = ((u128)s64[0] << 64) | s64[1];
  u128 initseq   = ((u128)s64[2] << 64) | s64[3];
  const u128 MULT = ((u128)0x2360ED051FC65DA4ULL << 64) | 0x4385DF649FCCF645ULL;
  u128 state = 0;
  u128 inc = (initseq << 1) | 1;
  state = state * MULT + inc;
  state += initstate;
  state = state * MULT + inc;
  for (int i = 0; i < NN; i++)
    for (int j = 0; j < NN; j++) {
      state = state * MULT + inc;
      uint64_t hi = (uint64_t)(state >> 64), lo = (uint64_t)state;
      unsigned rot = (unsigned)(hi >> 58);
      uint64_t xr = hi ^ lo;
      uint64_t out = (xr >> rot) | (xr << ((64u - rot) & 63u));
      double dv = (double)(out >> 11) * (1.0 / 9007199254740992.0);
      adj[i][j] = (dv < 0.25);
    }
}

// ---------------- device ----------------
struct NodeDesc {
  uint8_t node, npred, slot, flags;
  uint8_t pred_slot[31];
  uint8_t pad;
};
struct GroupArg { int n; NodeDesc d[32]; };   // one launch per LEVEL
struct FinalArg { int nf; uint8_t slot[32]; };

__device__ __forceinline__ float bf2f_lo(unsigned int w) {
  union { unsigned int u; float f; } c; c.u = w << 16; return c.f;
}
__device__ __forceinline__ float bf2f_hi(unsigned int w) {
  union { unsigned int u; float f; } c; c.u = w & 0xFFFF0000u; return c.f;
}
__device__ __forceinline__ float bf2f(unsigned short h) {
  union { unsigned int u; float f; } c; c.u = ((unsigned int)h) << 16; return c.f;
}
__device__ __forceinline__ unsigned short f2bf(float f) {
  union { float f; unsigned int u; } c; c.f = f;
  unsigned int u = c.u + 0x7FFFu + ((c.u >> 16) & 1u);  // RNE
  return (unsigned short)(u >> 16);
}

// R29: R28's 16-pos-everywhere regressed (321us): per-block FIXED cost
// (4096 fp32 pw loads + 4096 f2bf per block) doubled with block count;
// FETCH 34.5MB, VALUBusy 53%. Fix the fixed cost at the source:
//  - prep_kernel (once): pw -> bf16 PRE-SWIZZLED global (256KB, L2-hot)
//    + sigmoid(aggw) table. MFMA B-fragments read DIRECTLY from global;
//    pw LDS buffer + per-block convert/stage deleted everywhere.
//  - multi-node levels: back to the verified 32-pos geometry (784*n),
//    LDS 19.5KB -> 8 blocks/CU cap.
//  - single-node levels only: 16-pos chain_kernel (1568 blocks, 6.1/CU;
//    now cheap since fixed staging is gone).
// Math identical (same rounding + accumulation order) -> absmax unchanged.
__global__ void prep_kernel(const float* __restrict__ pwall,
                            const float* __restrict__ aggw,
                            unsigned short* __restrict__ pwswz,
                            float* __restrict__ wsig) {
  int i = blockIdx.x * 256 + threadIdx.x;
  if (i < NN * 4096) {
    int cc = i & 63, o = (i >> 6) & 63;
    int base = i & ~4095;
    pwswz[base + o * 64 + ((((cc >> 3) ^ (o & 7)) << 3) | (cc & 7))] = f2bf(pwall[i]);
  } else {
    int j = i - NN * 4096;
    if (j < NN * NN) wsig[j] = 1.f / (1.f + expf(-aggw[j]));
  }
}

__global__ __launch_bounds__(256) void input_kernel(
    GroupArg g,
    const float* __restrict__ x,
    const float* __restrict__ dwall,
    const unsigned short* __restrict__ pwswz,
    const float* __restrict__ gmall,
    const float* __restrict__ btall,
    const float* __restrict__ mnall,
    const float* __restrict__ vrall,
    unsigned short* __restrict__ wsb)
{
  __shared__ float xtile[9 * 17 * 64];                  // [9r][17c][64ch] relu(x) fp32
  __shared__ __align__(16) unsigned short tbuf[2048];   // t[32 pos][64 c] (bf16, swz)

  const int b = blockIdx.x & 7;       // image == XCD
  const int m = blockIdx.x >> 3;      // tile [0,98)
  const int t = threadIdx.x;
  const int ty = (m / 7) * 4;         // 14 y-tiles of 4 rows (output 56x56)
  const int tx = (m % 7) * 8;         // 7 x-tiles of 8 cols

  const int dwc = t & 63;
  const int pbase = (t >> 6) * 8;

  // ---- stage relu(x) tile once: aligned float4 loads (xbase = 2tx-4, 16B-aligned)
  {
    const int r0 = t >> 6;
    const float* xb = x + (size_t)(b * 64 + dwc) * 12544;
    const int iy0 = ty * 2 - 1;
    const int xbase = tx * 2 - 4;
    for (int iyL = r0; iyL < 9; iyL += 4) {
      int gy = iy0 + iyL;
      bool rowok = ((unsigned)gy < 112u);
      const float* row = xb + gy * 112 + xbase;
      float4 z = make_float4(0.f, 0.f, 0.f, 0.f);
      float4 v0 = z, v1 = z, v2 = z, v3 = z, v4 = z;
      if (rowok) {
        if (xbase >= 0) v0 = *(const float4*)(row);
        v1 = *(const float4*)(row + 4);
        v2 = *(const float4*)(row + 8);
        v3 = *(const float4*)(row + 12);
        v4 = *(const float4*)(row + 16);
      }
      float* dst = xtile + (iyL * 17) * 64 + dwc;
      dst[0 * 64]  = fmaxf(v0.w, 0.f);
      dst[1 * 64]  = fmaxf(v1.x, 0.f);
      dst[2 * 64]  = fmaxf(v1.y, 0.f);
      dst[3 * 64]  = fmaxf(v1.z, 0.f);
      dst[4 * 64]  = fmaxf(v1.w, 0.f);
      dst[5 * 64]  = fmaxf(v2.x, 0.f);
      dst[6 * 64]  = fmaxf(v2.y, 0.f);
      dst[7 * 64]  = fmaxf(v2.z, 0.f);
      dst[8 * 64]  = fmaxf(v2.w, 0.f);
      dst[9 * 64]  = fmaxf(v3.x, 0.f);
      dst[10 * 64] = fmaxf(v3.y, 0.f);
      dst[11 * 64] = fmaxf(v3.z, 0.f);
      dst[12 * 64] = fmaxf(v3.w, 0.f);
      dst[13 * 64] = fmaxf(v4.x, 0.f);
      dst[14 * 64] = fmaxf(v4.y, 0.f);
      dst[15 * 64] = fmaxf(v4.z, 0.f);
      dst[16 * 64] = fmaxf(v4.w, 0.f);
    }
  }

  for (int kk = 0; kk < g.n; kk++) {
    const NodeDesc nd = g.d[kk];
    const int node = nd.node;

    __syncthreads();  // B_a: xtile ready (kk=0); prev MFMA done with tbuf

    const float* k9 = dwall + (node * 64 + dwc) * 9;
    float kk9[9];
    #pragma unroll
    for (int q = 0; q < 9; q++) kk9[q] = k9[q];

    // depthwise stride-2 from LDS xtile
    float tv[8];
    #pragma unroll
    for (int jj = 0; jj < 8; jj++) {
      int p = pbase + jj;
      int py = p >> 3, px = p & 7;
      const float* r0 = xtile + ((py * 2) * 17 + px * 2) * 64 + dwc;
      tv[jj] = r0[0]    * kk9[0] + r0[64]   * kk9[1] + r0[128]  * kk9[2]
             + r0[1088] * kk9[3] + r0[1152] * kk9[4] + r0[1216] * kk9[5]
             + r0[2176] * kk9[6] + r0[2240] * kk9[7] + r0[2304] * kk9[8];
    }

    // t matrix bf16, granule-swizzled
    #pragma unroll
    for (int jj = 0; jj < 8; jj++) {
      int p = pbase + jj;
      tbuf[p * 64 + ((((dwc >> 3) ^ (p & 7)) << 3) | (dwc & 7))] = f2bf(tv[jj]);
    }
    __syncthreads();  // B_b: tbuf ready

    // MFMA pointwise: D[32 pos][64 oc] = t x pw^T ; B-fragments direct from global
    const int lane = t & 63;
    const int wave = t >> 6;
    const int mtile = wave & 1;
    const int npair = wave >> 1;
    const int lm = lane & 15;
    const int quad = lane >> 4;
    const unsigned short* pwn = pwswz + node * 4096;

    bf16x8 afrag[2];
    #pragma unroll
    for (int ks = 0; ks < 2; ks++) {
      int pos = mtile * 16 + lm;
      int gg = ks * 4 + quad;
      afrag[ks] = *(const bf16x8*)&tbuf[pos * 64 + ((gg ^ (pos & 7)) << 3)];
    }
    f32x4 acc[2];
    #pragma unroll
    for (int nt = 0; nt < 2; nt++) {
      acc[nt] = (f32x4){0.f, 0.f, 0.f, 0.f};
      int oc = (npair * 2 + nt) * 16 + lm;
      #pragma unroll
      for (int ks = 0; ks < 2; ks++) {
        int gg = ks * 4 + quad;
        bf16x8 bfrag = *(const bf16x8*)&pwn[oc * 64 + ((gg ^ (oc & 7)) << 3)];
        acc[nt] = __builtin_amdgcn_mfma_f32_16x16x32_bf16(afrag[ks], bfrag, acc[nt], 0, 0, 0);
      }
    }

    // BN + bf16 slot store
    unsigned short* slotp = wsb + (size_t)nd.slot * NODE_ELEMS;
    #pragma unroll
    for (int nt = 0; nt < 2; nt++) {
      int oc = (npair * 2 + nt) * 16 + lm;
      int gi = node * 64 + oc;
      float inv = gmall[gi] / sqrtf(vrall[gi] + 1e-5f);
      float mn = mnall[gi], btv = btall[gi];
      #pragma unroll
      for (int rr = 0; rr < 4; rr++) {
        int pos = mtile * 16 + quad * 4 + rr;
        int gy = ty + (pos >> 3), gx = tx + (pos & 7);
        size_t base = (((size_t)(b * 56 + gy)) * 56 + gx) * 64 + oc;
        slotp[base] = f2bf((acc[nt][rr] - mn) * inv + btv);
      }
    }
  }
}

// Multi-node levels: node-parallel, 32-pos tiles (4x8), halo 6x10x64 fp32.
// Grid 784*n. LDS 19.5KB -> 8 blocks/CU cap.
__global__ __launch_bounds__(256) void level_kernel(
    GroupArg g,
    const float* __restrict__ dwall,
    const unsigned short* __restrict__ pwswz,
    const float* __restrict__ gmall,
    const float* __restrict__ btall,
    const float* __restrict__ mnall,
    const float* __restrict__ vrall,
    const float* __restrict__ wsig,
    unsigned short* __restrict__ wsb)
{
  __shared__ float smem[3840];                          // halo [6r][10c][64ch] fp32
  __shared__ __align__(16) unsigned short tbuf[2048];   // t[32 pos][64 c] (bf16, swz)

  const int bid = blockIdx.x;
  const int nid = bid / 784;
  const int r   = bid - nid * 784;
  const int b = r & 7;                // image == XCD
  const int m = r >> 3;               // tile [0,98)
  const int t = threadIdx.x;
  const int ty = (m / 7) * 4;
  const int tx = (m % 7) * 8;

  const NodeDesc nd = g.d[nid];
  const int node = nd.node;

  const int dwc = t & 63;
  const int pbase = (t >> 6) * 8;

  const float* k9 = dwall + (node * 64 + dwc) * 9;
  float kk9[9];
  #pragma unroll
  for (int q = 0; q < 9; q++) kk9[q] = k9[q];

  // aggregate + relu into fp32 NHWC halo (480 units of 8 ch = 16 B)
  const int np = nd.npred;
  float sa[2][8];
  int off[2];
  bool inb[2];
  #pragma unroll
  for (int u = 0; u < 2; u++) {
    int idx = t + u * 256;
    bool valid = (u == 0) || (t < 224);
    int pos = idx >> 3, q8 = idx & 7;
    int hy = pos / 10, hx = pos - hy * 10;
    int gy = ty + hy - 1, gx = tx + hx - 1;
    inb[u] = valid && ((unsigned)gy < 56u) && ((unsigned)gx < 56u);
    off[u] = ((b * 56 + gy) * 56 + gx) * 64 + q8 * 8;
    #pragma unroll
    for (int q = 0; q < 8; q++) sa[u][q] = 0.f;
  }
  for (int p0 = 0; p0 < np; p0 += 4) {
    uint4 v[4][2];
    #pragma unroll
    for (int pp = 0; pp < 4; pp++) {
      if (p0 + pp < np) {
        const unsigned short* pb = wsb + (size_t)nd.pred_slot[p0 + pp] * NODE_ELEMS;
        #pragma unroll
        for (int u = 0; u < 2; u++)
          if (inb[u]) v[pp][u] = *(const uint4*)(pb + off[u]);
      }
    }
    float wv4[4];
    #pragma unroll
    for (int pp = 0; pp < 4; pp++)
      if (p0 + pp < np)
        wv4[pp] = (np == 1) ? 1.0f : wsig[node * 32 + p0 + pp];
    #pragma unroll
    for (int pp = 0; pp < 4; pp++) {
      if (p0 + pp < np) {
        float wv = wv4[pp];
        #pragma unroll
        for (int u = 0; u < 2; u++) {
          if (inb[u]) {
            sa[u][0] = fmaf(wv, bf2f_lo(v[pp][u].x), sa[u][0]);
            sa[u][1] = fmaf(wv, bf2f_hi(v[pp][u].x), sa[u][1]);
            sa[u][2] = fmaf(wv, bf2f_lo(v[pp][u].y), sa[u][2]);
            sa[u][3] = fmaf(wv, bf2f_hi(v[pp][u].y), sa[u][3]);
            sa[u][4] = fmaf(wv, bf2f_lo(v[pp][u].z), sa[u][4]);
            sa[u][5] = fmaf(wv, bf2f_hi(v[pp][u].z), sa[u][5]);
            sa[u][6] = fmaf(wv, bf2f_lo(v[pp][u].w), sa[u][6]);
            sa[u][7] = fmaf(wv, bf2f_hi(v[pp][u].w), sa[u][7]);
          }
        }
      }
    }
  }
  #pragma unroll
  for (int u = 0; u < 2; u++) {
    int idx = t + u * 256;
    if ((u == 0) || (t < 224)) {
      float4 s0 = make_float4(fmaxf(sa[u][0], 0.f), fmaxf(sa[u][1], 0.f),
                              fmaxf(sa[u][2], 0.f), fmaxf(sa[u][3], 0.f));
      float4 s1 = make_float4(fmaxf(sa[u][4], 0.f), fmaxf(sa[u][5], 0.f),
                              fmaxf(sa[u][6], 0.f), fmaxf(sa[u][7], 0.f));
      *(float4*)&smem[idx * 8] = s0;
      *(float4*)&smem[idx * 8 + 4] = s1;
    }
  }
  __syncthreads();   // B2: halo ready
  float tv[8];
  #pragma unroll
  for (int jj = 0; jj < 8; jj++) {
    int p = pbase + jj;
    int py = p >> 3, px = p & 7;
    const float* r0 = smem + (py * 10 + px) * 64 + dwc;
    tv[jj] = r0[0]    * kk9[0] + r0[64]   * kk9[1] + r0[128]  * kk9[2]
           + r0[640]  * kk9[3] + r0[704]  * kk9[4] + r0[768]  * kk9[5]
           + r0[1280] * kk9[6] + r0[1344] * kk9[7] + r0[1408] * kk9[8];
  }

  #pragma unroll
  for (int jj = 0; jj < 8; jj++) {
    int p = pbase + jj;
    tbuf[p * 64 + ((((dwc >> 3) ^ (p & 7)) << 3) | (dwc & 7))] = f2bf(tv[jj]);
  }
  __syncthreads();   // B3: tbuf ready

  // MFMA pointwise; B-fragments direct from pre-swizzled global (L2-hot)
  const int lane = t & 63;
  const int wave = t >> 6;
  const int mtile = wave & 1;
  const int npair = wave >> 1;
  const int lm = lane & 15;
  const int quad = lane >> 4;
  const unsigned short* pwn = pwswz + node * 4096;

  bf16x8 afrag[2];
  #pragma unroll
  for (int ks = 0; ks < 2; ks++) {
    int pos = mtile * 16 + lm;
    int gg = ks * 4 + quad;
    afrag[ks] = *(const bf16x8*)&tbuf[pos * 64 + ((gg ^ (pos & 7)) << 3)];
  }
  f32x4 acc[2];
  #pragma unroll
  for (int nt = 0; nt < 2; nt++) {
    acc[nt] = (f32x4){0.f, 0.f, 0.f, 0.f};
    int oc = (npair * 2 + nt) * 16 + lm;
    #pragma unroll
    for (int ks = 0; ks < 2; ks++) {
      int gg = ks * 4 + quad;
      bf16x8 bfrag = *(const bf16x8*)&pwn[oc * 64 + ((gg ^ (oc & 7)) << 3)];
      acc[nt] = __builtin_amdgcn_mfma_f32_16x16x32_bf16(afrag[ks], bfrag, acc[nt], 0, 0, 0);
    }
  }

  unsigned short* slotp = wsb + (size_t)nd.slot * NODE_ELEMS;
  #pragma unroll
  for (int nt = 0; nt < 2; nt++) {
    int oc = (npair * 2 + nt) * 16 + lm;
    int gi = node * 64 + oc;
    float inv = gmall[gi] / sqrtf(vrall[gi] + 1e-5f);
    float mn = mnall[gi], btv = btall[gi];
    #pragma unroll
    for (int rr = 0; rr < 4; rr++) {
      int pos = mtile * 16 + quad * 4 + rr;
      int gy = ty + (pos >> 3), gx = tx + (pos & 7);
      size_t base = (((size_t)(b * 56 + gy)) * 56 + gx) * 64 + oc;
      slotp[base] = f2bf((acc[nt][rr] - mn) * inv + btv);
    }
  }
}

// Single-node levels: 16-pos tiles (2x8), halo 4x10x64, grid 1568 (6.1/CU).
__global__ __launch_bounds__(256) void chain_kernel(
    GroupArg g,
    const float* __restrict__ dwall,
    const unsigned short* __restrict__ pwswz,
    const float* __restrict__ gmall,
    const float* __restrict__ btall,
    const float* __restrict__ mnall,
    const float* __restrict__ vrall,
    const float* __restrict__ wsig,
    unsigned short* __restrict__ wsb)
{
  __shared__ float smem[2560];                          // halo [4r][10c][64ch] fp32
  __shared__ __align__(16) unsigned short tbuf[1024];   // t[16 pos][64 c] (bf16, swz)

  const int bid = blockIdx.x;
  const int b = bid & 7;              // image == XCD
  const int m = bid >> 3;             // tile [0,196)
  const int t = threadIdx.x;
  const int ty = (m / 7) * 2;         // 28 y-tiles of 2 rows
  const int tx = (m % 7) * 8;

  const NodeDesc nd = g.d[0];
  const int node = nd.node;

  const int dwc = t & 63;
  const int pbase = (t >> 6) * 4;

  const float* k9 = dwall + (node * 64 + dwc) * 9;
  float kk9[9];
  #pragma unroll
  for (int q = 0; q < 9; q++) kk9[q] = k9[q];

  const int np = nd.npred;
  float sa[2][8];
  int off[2];
  bool inb[2];
  #pragma unroll
  for (int u = 0; u < 2; u++) {
    int idx = t + u * 256;
    bool valid = (u == 0) || (t < 64);
    int pos = idx >> 3, q8 = idx & 7;
    int hy = pos / 10, hx = pos - hy * 10;
    int gy = ty + hy - 1, gx = tx + hx - 1;
    inb[u] = valid && ((unsigned)gy < 56u) && ((unsigned)gx < 56u);
    off[u] = ((b * 56 + gy) * 56 + gx) * 64 + q8 * 8;
    #pragma unroll
    for (int q = 0; q < 8; q++) sa[u][q] = 0.f;
  }
  for (int p0 = 0; p0 < np; p0 += 4) {
    uint4 v[4][2];
    #pragma unroll
    for (int pp = 0; pp < 4; pp++) {
      if (p0 + pp < np) {
        const unsigned short* pb = wsb + (size_t)nd.pred_slot[p0 + pp] * NODE_ELEMS;
        #pragma unroll
        for (int u = 0; u < 2; u++)
          if (inb[u]) v[pp][u] = *(const uint4*)(pb + off[u]);
      }
    }
    float wv4[4];
    #pragma unroll
    for (int pp = 0; pp < 4; pp++)
      if (p0 + pp < np)
        wv4[pp] = (np == 1) ? 1.0f : wsig[node * 32 + p0 + pp];
    #pragma unroll
    for (int pp = 0; pp < 4; pp++) {
      if (p0 + pp < np) {
        float wv = wv4[pp];
        #pragma unroll
        for (int u = 0; u < 2; u++) {
          if (inb[u]) {
            sa[u][0] = fmaf(wv, bf2f_lo(v[pp][u].x), sa[u][0]);
            sa[u][1] = fmaf(wv, bf2f_hi(v[pp][u].x), sa[u][1]);
            sa[u][2] = fmaf(wv, bf2f_lo(v[pp][u].y), sa[u][2]);
            sa[u][3] = fmaf(wv, bf2f_hi(v[pp][u].y), sa[u][3]);
            sa[u][4] = fmaf(wv, bf2f_lo(v[pp][u].z), sa[u][4]);
            sa[u][5] = fmaf(wv, bf2f_hi(v[pp][u].z), sa[u][5]);
            sa[u][6] = fmaf(wv, bf2f_lo(v[pp][u].w), sa[u][6]);
            sa[u][7] = fmaf(wv, bf2f_hi(v[pp][u].w), sa[u][7]);
          }
        }
      }
    }
  }
  #pragma unroll
  for (int u = 0; u < 2; u++) {
    int idx = t + u * 256;
    if ((u == 0) || (t < 64)) {
      float4 s0 = make_float4(fmaxf(sa[u][0], 0.f), fmaxf(sa[u][1], 0.f),
                              fmaxf(sa[u][2], 0.f), fmaxf(sa[u][3], 0.f));
      float4 s1 = make_float4(fmaxf(sa[u][4], 0.f), fmaxf(sa[u][5], 0.f),
                              fmaxf(sa[u][6], 0.f), fmaxf(sa[u][7], 0.f));
      *(float4*)&smem[idx * 8] = s0;
      *(float4*)&smem[idx * 8 + 4] = s1;
    }
  }
  __syncthreads();   // B2: halo ready
  float tv[4];
  #pragma unroll
  for (int jj = 0; jj < 4; jj++) {
    int p = pbase + jj;
    int py = p >> 3, px = p & 7;
    const float* r0 = smem + (py * 10 + px) * 64 + dwc;
    tv[jj] = r0[0]    * kk9[0] + r0[64]   * kk9[1] + r0[128]  * kk9[2]
           + r0[640]  * kk9[3] + r0[704]  * kk9[4] + r0[768]  * kk9[5]
           + r0[1280] * kk9[6] + r0[1344] * kk9[7] + r0[1408] * kk9[8];
  }

  #pragma unroll
  for (int jj = 0; jj < 4; jj++) {
    int p = pbase + jj;
    tbuf[p * 64 + ((((dwc >> 3) ^ (p & 7)) << 3) | (dwc & 7))] = f2bf(tv[jj]);
  }
  __syncthreads();   // B3: tbuf ready

  const int lane = t & 63;
  const int wave = t >> 6;
  const int lm = lane & 15;
  const int quad = lane >> 4;
  const unsigned short* pwn = pwswz + node * 4096;

  bf16x8 afrag[2];
  #pragma unroll
  for (int ks = 0; ks < 2; ks++) {
    int pos = lm;
    int gg = ks * 4 + quad;
    afrag[ks] = *(const bf16x8*)&tbuf[pos * 64 + ((gg ^ (pos & 7)) << 3)];
  }
  const int oc = wave * 16 + lm;
  f32x4 acc = (f32x4){0.f, 0.f, 0.f, 0.f};
  #pragma unroll
  for (int ks = 0; ks < 2; ks++) {
    int gg = ks * 4 + quad;
    bf16x8 bfrag = *(const bf16x8*)&pwn[oc * 64 + ((gg ^ (oc & 7)) << 3)];
    acc = __builtin_amdgcn_mfma_f32_16x16x32_bf16(afrag[ks], bfrag, acc, 0, 0, 0);
  }

  unsigned short* slotp = wsb + (size_t)nd.slot * NODE_ELEMS;
  {
    int gi = node * 64 + oc;
    float inv = gmall[gi] / sqrtf(vrall[gi] + 1e-5f);
    float mn = mnall[gi], btv = btall[gi];
    #pragma unroll
    for (int rr = 0; rr < 4; rr++) {
      int pos = quad * 4 + rr;
      int gy = ty + (pos >> 3), gx = tx + (pos & 7);
      size_t base = (((size_t)(b * 56 + gy)) * 56 + gx) * 64 + oc;
      slotp[base] = f2bf((acc[rr] - mn) * inv + btv);
    }
  }
}

// Mean of FINAL bf16 slots (fp32 accumulate) -> NCHW d_out.
__global__ __launch_bounds__(256) void finalize_kernel(
    FinalArg fa, const unsigned short* __restrict__ wsb,
    float* __restrict__ out, float inv_nf)
{
  __shared__ float lds[64 * 29];
  const int bid = blockIdx.x;
  const int half = bid & 1;
  const int by = bid >> 1;
  const int b = by / 56, y = by - b * 56;
  const int x0 = half * 28;
  const size_t rbase = ((((size_t)b * 56 + y) * 56) + x0) * 64;
  const int t = threadIdx.x;
  const int nf = fa.nf;

  if (t < 224) {
    const int xx = t >> 3, q8 = t & 7;
    const unsigned short* p0 = wsb + rbase + xx * 64 + q8 * 8;
    float s0 = 0.f, s1 = 0.f, s2 = 0.f, s3 = 0.f,
          s4 = 0.f, s5 = 0.f, s6 = 0.f, s7 = 0.f;
    for (int f0 = 0; f0 < nf; f0 += 4) {
      uint4 va, vb, vc, vd;
      if (f0 + 0 < nf) va = *(const uint4*)(p0 + (size_t)fa.slot[f0 + 0] * NODE_ELEMS);
      if (f0 + 1 < nf) vb = *(const uint4*)(p0 + (size_t)fa.slot[f0 + 1] * NODE_ELEMS);
      if (f0 + 2 < nf) vc = *(const uint4*)(p0 + (size_t)fa.slot[f0 + 2] * NODE_ELEMS);
      if (f0 + 3 < nf) vd = *(const uint4*)(p0 + (size_t)fa.slot[f0 + 3] * NODE_ELEMS);
      if (f0 + 0 < nf) {
        s0 += bf2f_lo(va.x); s1 += bf2f_hi(va.x); s2 += bf2f_lo(va.y); s3 += bf2f_hi(va.y);
        s4 += bf2f_lo(va.z); s5 += bf2f_hi(va.z); s6 += bf2f_lo(va.w); s7 += bf2f_hi(va.w);
      }
      if (f0 + 1 < nf) {
        s0 += bf2f_lo(vb.x); s1 += bf2f_hi(vb.x); s2 += bf2f_lo(vb.y); s3 += bf2f_hi(vb.y);
        s4 += bf2f_lo(vb.z); s5 += bf2f_hi(vb.z); s6 += bf2f_lo(vb.w); s7 += bf2f_hi(vb.w);
      }
      if (f0 + 2 < nf) {
        s0 += bf2f_lo(vc.x); s1 += bf2f_hi(vc.x); s2 += bf2f_lo(vc.y); s3 += bf2f_hi(vc.y);
        s4 += bf2f_lo(vc.z); s5 += bf2f_hi(vc.z); s6 += bf2f_lo(vc.w); s7 += bf2f_hi(vc.w);
      }
      if (f0 + 3 < nf) {
        s0 += bf2f_lo(vd.x); s1 += bf2f_hi(vd.x); s2 += bf2f_lo(vd.y); s3 += bf2f_hi(vd.y);
        s4 += bf2f_lo(vd.z); s5 += bf2f_hi(vd.z); s6 += bf2f_lo(vd.w); s7 += bf2f_hi(vd.w);
      }
    }
    float* dl = lds + (q8 * 8) * 29 + xx;
    dl[0 * 29] = s0 * inv_nf; dl[1 * 29] = s1 * inv_nf;
    dl[2 * 29] = s2 * inv_nf; dl[3 * 29] = s3 * inv_nf;
    dl[4 * 29] = s4 * inv_nf; dl[5 * 29] = s5 * inv_nf;
    dl[6 * 29] = s6 * inv_nf; dl[7 * 29] = s7 * inv_nf;
  }
  __syncthreads();
  float* dst = out + (size_t)b * 64 * 3136 + (size_t)y * 56 + x0;
  for (int j = t; j < 1792; j += 256) {
    int c = j / 28, xx = j - c * 28;
    dst[(size_t)c * 3136 + xx] = lds[c * 29 + xx];
  }
}

// ---------------- launcher ----------------
extern "C" void kernel_launch(void* const* d_in, const int* in_sizes, int n_in,
                              void* d_out, int out_size, void* d_ws, size_t ws_size,
                              hipStream_t stream) {
  (void)in_sizes; (void)n_in; (void)ws_size; (void)out_size;
  const float* x     = (const float*)d_in[0];
  const float* dw    = (const float*)d_in[1];
  const float* pw    = (const float*)d_in[2];
  const float* gamma = (const float*)d_in[3];
  const float* beta  = (const float*)d_in[4];
  const float* mean  = (const float*)d_in[5];
  const float* var   = (const float*)d_in[6];
  const float* aggw  = (const float*)d_in[7];
  unsigned short* wsb = (unsigned short*)d_ws;
  float* out = (float*)d_out;

  bool adj[NN][NN];
  compute_adj(adj);

  int npred[NN], preds[NN][NN], nsucc[NN], ispan[NN], level[NN];
  for (int j = 0; j < NN; j++) {
    npred[j] = 0;
    for (int i = 0; i < j; i++) if (adj[i][j]) preds[j][npred[j]++] = i;
  }
  for (int i = 0; i < NN; i++) {
    nsucc[i] = 0; ispan[i] = NN;
    int mx = -1;
    for (int j = i + 1; j < NN; j++) if (adj[i][j]) { nsucc[i]++; mx = j; }
    if (nsucc[i] > 0) ispan[i] = mx;
  }
  int maxlev = 0;
  for (int j = 0; j < NN; j++) {
    int lv = 0;
    for (int p = 0; p < npred[j]; p++) {
      int cand = level[preds[j][p]] + 1;
      if (cand > lv) lv = cand;
    }
    level[j] = lv;
    if (lv > maxlev) maxlev = lv;
  }
  bool isfinal[NN]; int nf = 0;
  for (int i = 0; i < NN; i++) { isfinal[i] = (ispan[i] >= NN - 1); if (isfinal[i]) nf++; }
  int lastlvl[NN];
  for (int i = 0; i < NN; i++) {
    lastlvl[i] = -1;
    for (int j = i + 1; j < NN; j++) if (adj[i][j] && level[j] > lastlvl[i]) lastlvl[i] = level[j];
  }
  // slot allocation: every node gets a slot; FINAL slots never freed.
  int slot[NN]; bool used[NN];
  for (int s = 0; s < NN; s++) used[s] = false;
  for (int L = 0; L <= maxlev; L++) {
    for (int i = 0; i < NN; i++) {
      if (level[i] != L) continue;
      int s = 0; while (used[s]) s++;
      used[s] = true; slot[i] = s;
    }
    for (int i = 0; i < NN; i++)
      if (level[i] <= L && !isfinal[i] && lastlvl[i] == L)
        used[slot[i]] = false;
  }
  int maxs = 0;
  for (int i = 0; i < NN; i++) if (slot[i] > maxs) maxs = slot[i];

  // workspace layout: slots [0..maxs], then pw bf16 swizzled (128K shorts),
  // then sigmoid table (1024 floats)
  unsigned short* pwswz = wsb + (size_t)(maxs + 1) * NODE_ELEMS;
  float* wsig = (float*)(pwswz + NN * 4096);

  float inv_nf = 1.0f / (float)nf;

  prep_kernel<<<516, 256, 0, stream>>>(pw, aggw, pwswz, wsig);

  for (int L = 0; L <= maxlev; L++) {
    GroupArg g; g.n = 0;
    for (int i = 0; i < NN; i++) {
      if (level[i] != L) continue;
      NodeDesc& nd = g.d[g.n++];
      nd.node = (uint8_t)i;
      nd.npred = (uint8_t)npred[i];
      nd.slot = (uint8_t)slot[i];
      nd.flags = 0;
      for (int p = 0; p < npred[i]; p++) nd.pred_slot[p] = (uint8_t)slot[preds[i][p]];
    }
    if (g.n > 0) {
      if (L == 0) {
        input_kernel<<<784, 256, 0, stream>>>(g, x, dw, pwswz, gamma, beta,
                                              mean, var, wsb);
      } else if (g.n == 1) {
        chain_kernel<<<1568, 256, 0, stream>>>(g, dw, pwswz, gamma, beta,
                                               mean, var, wsig, wsb);
      } else {
        level_kernel<<<784 * g.n, 256, 0, stream>>>(g, dw, pwswz, gamma, beta,
                                                    mean, var, wsig, wsb);
      }
    }
  }

  FinalArg fa; fa.nf = 0;
  for (int i = 0; i < NN; i++) if (isfinal[i]) fa.slot[fa.nf++] = (uint8_t)slot[i];
  finalize_kernel<<<896, 256, 0, stream>>>(fa, wsb, out, inv_nf);
}